// Round 4
// baseline (443.094 us; speedup 1.0000x reference)
//
#include <hip/hip_runtime.h>
#include <hip/hip_bf16.h>

typedef unsigned short u16;
typedef unsigned int u32;
typedef __bf16 bf16x8_t __attribute__((ext_vector_type(8)));
typedef float fx4 __attribute__((ext_vector_type(4)));
typedef float fx16 __attribute__((ext_vector_type(16)));
typedef u16 u16x8_t __attribute__((ext_vector_type(8)));
typedef u32 u32x2_t __attribute__((ext_vector_type(2)));
typedef u32 u32x4_t __attribute__((ext_vector_type(4)));

#define SCALE_Q 0.17677669529663687f

__device__ __forceinline__ u16 f2bu(float f) {
  __bf16 h = (__bf16)f;
  return __builtin_bit_cast(u16, h);
}
__device__ __forceinline__ float bu2f(u16 b) {
  return __builtin_bit_cast(float, (u32)b << 16);
}
// swap a.lanes[32:63] <-> b.lanes[0:31]
__device__ __forceinline__ void plswap(u32& a, u32& b) {
  u32x2_t r = __builtin_amdgcn_permlane32_swap(a, b, false, false);
  a = r[0]; b = r[1];
}

#define GLD16(gp, lp) __builtin_amdgcn_global_load_lds( \
    (const __attribute__((address_space(1))) void*)(gp), \
    (__attribute__((address_space(3))) void*)(lp), 16, 0, 0)

// ---------------- prep: x permute + convert to bf16 [75264][256] ----------------
__global__ void prep_x(const float* __restrict__ x, u16* __restrict__ xw) {
  int t = blockIdx.x * 256 + threadIdx.x;      // 75264*32 threads, 8 elems each
  int m = t >> 5, c8 = (t & 31) * 8;
  int b = m / 294, n = m % 294;
  int hx = b >> 4, wy = b & 15;
  int l = n / 49, rem = n % 49;
  int w1 = rem / 7, w2 = rem % 7;
  size_t xoff = (((((size_t)l * 16 + hx) * 16 + wy) * 7 + w1) * 7 + w2) * 256 + c8;
  const float4* src = (const float4*)(x + xoff);
  float4 v0 = src[0], v1 = src[1];
  u16x8_t o;
  o[0] = f2bu(v0.x); o[1] = f2bu(v0.y); o[2] = f2bu(v0.z); o[3] = f2bu(v0.w);
  o[4] = f2bu(v1.x); o[5] = f2bu(v1.y); o[6] = f2bu(v1.z); o[7] = f2bu(v1.w);
  *(u16x8_t*)(xw + (size_t)m * 256 + c8) = o;
}

// ---------------- prep: weights -> bf16 (fold softmax SCALE into q-rows) -------
__global__ void prep_w(const float* __restrict__ wqkv, const float* __restrict__ wout,
                       u16* __restrict__ bqkv, u16* __restrict__ bwout) {
  int t = blockIdx.x * 256 + threadIdx.x;      // 262144 threads
  if (t < 196608) {
    float v = wqkv[t];
    if (t < 65536) v *= SCALE_Q;               // rows 0..255 are Q rows
    bqkv[t] = f2bu(v);
  } else {
    int i = t - 196608;
    bwout[i] = f2bu(wout[i]);
  }
}

// -------- prep: bias in 32x32 MFMA C-fragment layout [h][s10][t10][lane64][16] --
// S^T fragment: col = lane&31 = query, row = (r&3)+8*(r>>2)+4*(lane>>5) = key.
__global__ void prep_bias(const float* __restrict__ table, u16* __restrict__ bias_pre) {
  int t = blockIdx.x * 256 + threadIdx.x;      // 8*10*10*64 = 51200 threads
  int lane = t & 63;
  int rest = t >> 6;
  int tile = rest % 10; rest /= 10;
  int s = rest % 10; int h = rest / 10;
  int q = s * 32 + (lane & 31); if (q > 293) q = 293;   // padded q rows: clamp
  int l1 = q / 49, r1 = q % 49, a1 = r1 / 7, b1 = r1 % 7;
  u16x8_t o0, o1;
#pragma unroll
  for (int r = 0; r < 16; ++r) {
    int key = tile * 32 + (r & 3) + 8 * (r >> 2) + 4 * (lane >> 5);
    float v;
    if (key >= 294) {
      v = -1e30f;                              // mask padded key rows
    } else {
      int l2 = key / 49, r2 = key % 49, a2 = r2 / 7, b2 = r2 % 7;
      int idx = (l1 - l2 + 5) * 169 + (a1 - a2 + 6) * 13 + (b1 - b2 + 6);
      v = table[idx * 8 + h];
    }
    if (r < 8) o0[r] = f2bu(v); else o1[r - 8] = f2bu(v);
  }
  u16* dst = bias_pre + (size_t)t * 16;
  *(u16x8_t*)(dst) = o0;
  *(u16x8_t*)(dst + 8) = o1;
}

// ---------------- 128x128x32 bf16 MFMA GEMM (B^T layout: out = A @ B^T) --------
template <int EPI>
__global__ __launch_bounds__(256, 2) void gemm128(const u16* __restrict__ A,
                                                  const u16* __restrict__ Bw,
                                                  u16* __restrict__ Cb,
                                                  float* __restrict__ Cf) {
  __shared__ u16 sA[128 * 32];
  __shared__ u16 sB[128 * 32];
  const int tid = threadIdx.x, lane = tid & 63, wave = tid >> 6;
  const int wr = wave >> 1, wc = wave & 1;
  const int tm = blockIdx.x, tn = blockIdx.y;
  fx4 acc[4][4] = {};
#pragma unroll 1
  for (int kt = 0; kt < 8; ++kt) {
    __syncthreads();
#pragma unroll
    for (int rnd = 0; rnd < 2; ++rnd) {
      int o = rnd * 4096 + tid * 16;
      int row = o >> 6, cb = o & 63;
      const u16* gA = A + (size_t)(tm * 128 + row) * 256 + kt * 32 + (cb >> 1);
      const u16* gB = Bw + (size_t)(tn * 128 + row) * 256 + kt * 32 + (cb >> 1);
      GLD16(gA, (char*)sA + o);
      GLD16(gB, (char*)sB + o);
    }
    __syncthreads();
    bf16x8_t af[4], bfr[4];
#pragma unroll
    for (int i = 0; i < 4; ++i)
      af[i] = *(const bf16x8_t*)&sA[(wr * 64 + i * 16 + (lane & 15)) * 32 + (lane >> 4) * 8];
#pragma unroll
    for (int j = 0; j < 4; ++j)
      bfr[j] = *(const bf16x8_t*)&sB[(wc * 64 + j * 16 + (lane & 15)) * 32 + (lane >> 4) * 8];
#pragma unroll
    for (int i = 0; i < 4; ++i)
#pragma unroll
      for (int j = 0; j < 4; ++j)
        acc[i][j] = __builtin_amdgcn_mfma_f32_16x16x32_bf16(af[i], bfr[j], acc[i][j], 0, 0, 0);
  }
  const int r0 = tm * 128 + wr * 64, c0 = tn * 128 + wc * 64;
#pragma unroll
  for (int i = 0; i < 4; ++i) {
#pragma unroll
    for (int j = 0; j < 4; ++j) {
#pragma unroll
      for (int r = 0; r < 4; ++r) {
        int row = r0 + i * 16 + (lane >> 4) * 4 + r;
        int col = c0 + j * 16 + (lane & 15);
        float v = acc[i][j][r];
        if (EPI == 0) {
          Cb[(size_t)row * 768 + col] = f2bu(v);
        } else {
          int b = row / 294, n = row % 294;
          int hx = b >> 4, wy = b & 15;
          int l = n / 49, rem = n % 49, w1 = rem / 7, w2 = rem % 7;
          size_t off = (((((size_t)l * 16 + hx) * 16 + wy) * 7 + w1) * 7 + w2) * 256 + col;
          Cf[off] = v;
        }
      }
    }
  }
}

// ---------------- fused attention: one block per (window, head) ----------------
// Swapped-operand 32x32x16: S^T = mfma(K,Q) -> lane-local softmax -> permlane
// redistribution -> O = mfma(P, V^T).  LDS: only swizzled V^T (21 KB).
// VT byte addr: d*656 + ((d>>3)&3)*32 + tok*2  (write ~2-way, b128 read conflict-free)
__device__ __forceinline__ int vt_byte(int d, int tok) {
  return d * 656 + ((d >> 3) & 3) * 32 + tok * 2;
}

__global__ __launch_bounds__(256, 2) void attn(const u16* __restrict__ qkv,
                                               const u16* __restrict__ bias_pre,
                                               u16* __restrict__ aout) {
  __shared__ __align__(16) u16 VT[10560];      // 21120 B
  const int blk = blockIdx.x;
  const int b = blk >> 3, h = blk & 7;
  const int tid = threadIdx.x, lane = tid & 63, wave = tid >> 6;
  const int l31 = lane & 31, g5 = lane >> 5;
  const size_t base = (size_t)b * 294 * 768;

  // build swizzled V^T (zero-fill padded tokens 294..319)
  for (int i = tid; i < 1280; i += 256) {
    int tok = i >> 2, c8 = (i & 3) * 8;
    u16x8_t v;
    if (tok < 294) {
      v = *(const u16x8_t*)(qkv + base + (size_t)tok * 768 + 512 + h * 32 + c8);
    } else {
#pragma unroll
      for (int j = 0; j < 8; ++j) v[j] = 0;
    }
#pragma unroll
    for (int j = 0; j < 8; ++j)
      *(u16*)((char*)VT + vt_byte(c8 + j, tok)) = v[j];
  }
  __syncthreads();

#pragma unroll 1
  for (int s = wave; s < 10; s += 4) {
    // Q B-fragment (row = l31 = query, k = d), two d-halves
    int qr = s * 32 + l31; if (qr > 293) qr = 293;
    const u16* qb = qkv + base + (size_t)qr * 768 + h * 32 + g5 * 8;
    bf16x8_t qf0 = *(const bf16x8_t*)(qb);
    bf16x8_t qf1 = *(const bf16x8_t*)(qb + 16);

    // S^T = K Q^T + bias : acc[t] covers keys t*32..t*32+31 for query l31
    fx16 acc[10];
    const u16* bp = bias_pre + ((size_t)((h * 10 + s) * 10) * 64 + lane) * 16;
#pragma unroll
    for (int t = 0; t < 10; ++t) {
      u16x8_t b0 = *(const u16x8_t*)(bp + t * 1024);
      u16x8_t b1 = *(const u16x8_t*)(bp + t * 1024 + 8);
      fx16 a;
#pragma unroll
      for (int j = 0; j < 8; ++j) { a[j] = bu2f(b0[j]); a[8 + j] = bu2f(b1[j]); }
      int kr = t * 32 + l31; if (kr > 293) kr = 293;
      const u16* kb = qkv + base + (size_t)kr * 768 + 256 + h * 32 + g5 * 8;
      bf16x8_t kf0 = *(const bf16x8_t*)(kb);
      bf16x8_t kf1 = *(const bf16x8_t*)(kb + 16);
      a = __builtin_amdgcn_mfma_f32_32x32x16_bf16(kf0, qf0, a, 0, 0, 0);
      a = __builtin_amdgcn_mfma_f32_32x32x16_bf16(kf1, qf1, a, 0, 0, 0);
      acc[t] = a;
    }

    // lane-local softmax over 160 values + one cross-half merge
    float mv = acc[0][0];
#pragma unroll
    for (int t = 0; t < 10; ++t)
#pragma unroll
      for (int r = 0; r < 16; ++r) mv = fmaxf(mv, acc[t][r]);
    mv = fmaxf(mv, __shfl_xor(mv, 32));

    float sv = 0.f;
    u32 pk[10][8];
#pragma unroll
    for (int t = 0; t < 10; ++t) {
      float e[16];
#pragma unroll
      for (int r = 0; r < 16; ++r) { e[r] = __expf(acc[t][r] - mv); sv += e[r]; }
#pragma unroll
      for (int j = 0; j < 8; ++j)
        pk[t][j] = (u32)f2bu(e[2 * j]) | ((u32)f2bu(e[2 * j + 1]) << 16);
    }
    sv += __shfl_xor(sv, 32);
    float inv = 1.0f / sv;

    // O = P V : A-frag via permlane32_swap redistribution, B-frag from VT
    fx16 O;
#pragma unroll
    for (int r = 0; r < 16; ++r) O[r] = 0.f;
#pragma unroll
    for (int t = 0; t < 10; ++t) {
#pragma unroll
      for (int kh = 0; kh < 2; ++kh) {
        u32 w0 = pk[t][kh * 4 + 0], w1 = pk[t][kh * 4 + 1];
        u32 w2 = pk[t][kh * 4 + 2], w3 = pk[t][kh * 4 + 3];
        plswap(w0, w2);                        // g5=0: k0-7 ; g5=1: k8-15 (of 16-key half)
        plswap(w1, w3);
        u32x4_t w; w[0] = w0; w[1] = w1; w[2] = w2; w[3] = w3;
        bf16x8_t pf = __builtin_bit_cast(bf16x8_t, w);
        bf16x8_t vf = *(const bf16x8_t*)((char*)VT + vt_byte(l31, t * 32 + kh * 16 + g5 * 8));
        O = __builtin_amdgcn_mfma_f32_32x32x16_bf16(pf, vf, O, 0, 0, 0);
      }
    }

    // normalize + store: C-layout row=(r&3)+8*(r>>2)+4*g5 = query, col=l31 = dim
#pragma unroll
    for (int r = 0; r < 16; ++r) {
      int qrow = (r & 3) + 8 * (r >> 2) + 4 * g5;
      int qo = s * 32 + qrow;
      if (qo < 294) {
        float iv = __shfl(inv, qrow);
        aout[((size_t)b * 294 + qo) * 256 + h * 32 + l31] = f2bu(O[r] * iv);
      }
    }
  }
}

extern "C" void kernel_launch(void* const* d_in, const int* in_sizes, int n_in,
                              void* d_out, int out_size, void* d_ws, size_t ws_size,
                              hipStream_t stream) {
  (void)in_sizes; (void)n_in; (void)out_size; (void)ws_size;
  const float* x    = (const float*)d_in[0];
  const float* wqkv = (const float*)d_in[1];
  const float* wout = (const float*)d_in[2];
  const float* btab = (const float*)d_in[3];
  float* out = (float*)d_out;
  char* ws = (char*)d_ws;
  u16* xw    = (u16*)(ws);                     // 75264*256*2   = 38,535,168
  u16* bqkv  = (u16*)(ws + 38535168);          // 768*256*2     =    393,216
  u16* bwout = (u16*)(ws + 38928384);          // 256*256*2     =    131,072
  u16* biasp = (u16*)(ws + 39059456);          // 51200*16*2    =  1,638,400
  u16* qkv   = (u16*)(ws + 40697856);          // 75264*768*2   = 115,605,504 (tot ~149MB)
  u16* aout  = xw;                             // reuse: xw dead after gemm<0>

  prep_x<<<9408, 256, 0, stream>>>(x, xw);
  prep_w<<<1024, 256, 0, stream>>>(wqkv, wout, bqkv, bwout);
  prep_bias<<<200, 256, 0, stream>>>(btab, biasp);
  gemm128<0><<<dim3(588, 6), 256, 0, stream>>>(xw, bqkv, qkv, nullptr);
  attn<<<2048, 256, 0, stream>>>(qkv, biasp, aout);
  gemm128<1><<<dim3(588, 2), 256, 0, stream>>>(aout, bwout, nullptr, out);
}

// Round 5
// 334.210 us; speedup vs baseline: 1.3258x; 1.3258x over previous
//
#include <hip/hip_runtime.h>
#include <hip/hip_bf16.h>

typedef unsigned short u16;
typedef unsigned int u32;
typedef __bf16 bf16x8_t __attribute__((ext_vector_type(8)));
typedef float fx4 __attribute__((ext_vector_type(4)));
typedef float fx16 __attribute__((ext_vector_type(16)));
typedef u16 u16x8_t __attribute__((ext_vector_type(8)));
typedef u32 u32x2_t __attribute__((ext_vector_type(2)));
typedef u32 u32x4_t __attribute__((ext_vector_type(4)));

// (1/sqrt(32)) * log2(e): fold softmax scale AND exp->exp2 conversion into Q
#define QSCALE 0.25500276676267216f
#define LOG2E 1.4426950408889634f

__device__ __forceinline__ u16 f2bu(float f) {
  __bf16 h = (__bf16)f;
  return __builtin_bit_cast(u16, h);
}
__device__ __forceinline__ float bu2f(u16 b) {
  return __builtin_bit_cast(float, (u32)b << 16);
}
// swap a.lanes[32:63] <-> b.lanes[0:31]
__device__ __forceinline__ void plswap(u32& a, u32& b) {
  u32x2_t r = __builtin_amdgcn_permlane32_swap(a, b, false, false);
  a = r[0]; b = r[1];
}

#define GLD16(gp, lp) __builtin_amdgcn_global_load_lds( \
    (const __attribute__((address_space(1))) void*)(gp), \
    (__attribute__((address_space(3))) void*)(lp), 16, 0, 0)

// ---------------- prep: weights -> bf16 (fold QSCALE into q-rows) --------------
__global__ void prep_w(const float* __restrict__ wqkv, const float* __restrict__ wout,
                       u16* __restrict__ bqkv, u16* __restrict__ bwout) {
  int t = blockIdx.x * 256 + threadIdx.x;      // 262144 threads
  if (t < 196608) {
    float v = wqkv[t];
    if (t < 65536) v *= QSCALE;                // rows 0..255 are Q rows
    bqkv[t] = f2bu(v);
  } else {
    int i = t - 196608;
    bwout[i] = f2bu(wout[i]);
  }
}

// -------- prep: bias in 32x32 MFMA C-fragment layout [h][s10][t10][lane64][16] --
// S^T fragment: col = lane&31 = query, row = (r&3)+8*(r>>2)+4*(lane>>5) = key.
// Bias pre-multiplied by log2(e) (exp2-domain softmax).
__global__ void prep_bias(const float* __restrict__ table, u16* __restrict__ bias_pre) {
  int t = blockIdx.x * 256 + threadIdx.x;      // 8*10*10*64 = 51200 threads
  int lane = t & 63;
  int rest = t >> 6;
  int tile = rest % 10; rest /= 10;
  int s = rest % 10; int h = rest / 10;
  int q = s * 32 + (lane & 31); if (q > 293) q = 293;   // padded q rows: clamp
  int l1 = q / 49, r1 = q % 49, a1 = r1 / 7, b1 = r1 % 7;
  u16x8_t o0, o1;
#pragma unroll
  for (int r = 0; r < 16; ++r) {
    int key = tile * 32 + (r & 3) + 8 * (r >> 2) + 4 * (lane >> 5);
    float v;
    if (key >= 294) {
      v = -1e30f;                              // mask padded key rows (exp2 -> 0)
    } else {
      int l2 = key / 49, r2 = key % 49, a2 = r2 / 7, b2 = r2 % 7;
      int idx = (l1 - l2 + 5) * 169 + (a1 - a2 + 6) * 13 + (b1 - b2 + 6);
      v = table[idx * 8 + h] * LOG2E;
    }
    if (r < 8) o0[r] = f2bu(v); else o1[r - 8] = f2bu(v);
  }
  u16* dst = bias_pre + (size_t)t * 16;
  *(u16x8_t*)(dst) = o0;
  *(u16x8_t*)(dst + 8) = o1;
}

// ------- QKV GEMM with fused x-permute: A from x (f32, scattered rows), --------
// ------- on-the-fly bf16 convert + ds_write; B via global_load_lds. -----------
__global__ __launch_bounds__(256, 2) void gemm_qkv(const float* __restrict__ X,
                                                   const u16* __restrict__ Bw,
                                                   u16* __restrict__ C) {
  __shared__ u16 sA[128 * 32];
  __shared__ u16 sB[128 * 32];
  const int tid = threadIdx.x, lane = tid & 63, wave = tid >> 6;
  const int wr = wave >> 1, wc = wave & 1;
  const int tm = blockIdx.x, tn = blockIdx.y;
  // per-thread A source: row rnd*64+(tid>>2) of this M-tile, elems (tid&3)*8..+7
  size_t xb[2];
#pragma unroll
  for (int rnd = 0; rnd < 2; ++rnd) {
    int row = rnd * 64 + (tid >> 2);
    int m = tm * 128 + row;
    int b = m / 294, n = m % 294;
    int hx = b >> 4, wy = b & 15;
    int l = n / 49, rem = n % 49, w1 = rem / 7, w2 = rem % 7;
    xb[rnd] = (((((size_t)l * 16 + hx) * 16 + wy) * 7 + w1) * 7 + w2) * 256 + (tid & 3) * 8;
  }
  fx4 acc[4][4] = {};
#pragma unroll 1
  for (int kt = 0; kt < 8; ++kt) {
    __syncthreads();
#pragma unroll
    for (int rnd = 0; rnd < 2; ++rnd) {
      int o = rnd * 4096 + tid * 16;
      const float4* src = (const float4*)(X + xb[rnd] + kt * 32);
      float4 v0 = src[0], v1 = src[1];
      u16x8_t a8;
      a8[0] = f2bu(v0.x); a8[1] = f2bu(v0.y); a8[2] = f2bu(v0.z); a8[3] = f2bu(v0.w);
      a8[4] = f2bu(v1.x); a8[5] = f2bu(v1.y); a8[6] = f2bu(v1.z); a8[7] = f2bu(v1.w);
      *(u16x8_t*)((char*)sA + o) = a8;         // ds_write_b128
      int row = o >> 6, cb = o & 63;
      const u16* gB = Bw + (size_t)(tn * 128 + row) * 256 + kt * 32 + (cb >> 1);
      GLD16(gB, (char*)sB + o);
    }
    __syncthreads();
    bf16x8_t af[4], bfr[4];
#pragma unroll
    for (int i = 0; i < 4; ++i)
      af[i] = *(const bf16x8_t*)&sA[(wr * 64 + i * 16 + (lane & 15)) * 32 + (lane >> 4) * 8];
#pragma unroll
    for (int j = 0; j < 4; ++j)
      bfr[j] = *(const bf16x8_t*)&sB[(wc * 64 + j * 16 + (lane & 15)) * 32 + (lane >> 4) * 8];
#pragma unroll
    for (int i = 0; i < 4; ++i)
#pragma unroll
      for (int j = 0; j < 4; ++j)
        acc[i][j] = __builtin_amdgcn_mfma_f32_16x16x32_bf16(af[i], bfr[j], acc[i][j], 0, 0, 0);
  }
  const int r0 = tm * 128 + wr * 64, c0 = tn * 128 + wc * 64;
#pragma unroll
  for (int i = 0; i < 4; ++i)
#pragma unroll
    for (int j = 0; j < 4; ++j)
#pragma unroll
      for (int r = 0; r < 4; ++r) {
        int row = r0 + i * 16 + (lane >> 4) * 4 + r;
        int col = c0 + j * 16 + (lane & 15);
        C[(size_t)row * 768 + col] = f2bu(acc[i][j][r]);
      }
}

// ---------------- output-projection GEMM (A = aout bf16, scatter-f32 epilogue) --
__global__ __launch_bounds__(256, 2) void gemm_proj(const u16* __restrict__ A,
                                                    const u16* __restrict__ Bw,
                                                    float* __restrict__ Cf) {
  __shared__ u16 sA[128 * 32];
  __shared__ u16 sB[128 * 32];
  const int tid = threadIdx.x, lane = tid & 63, wave = tid >> 6;
  const int wr = wave >> 1, wc = wave & 1;
  const int tm = blockIdx.x, tn = blockIdx.y;
  fx4 acc[4][4] = {};
#pragma unroll 1
  for (int kt = 0; kt < 8; ++kt) {
    __syncthreads();
#pragma unroll
    for (int rnd = 0; rnd < 2; ++rnd) {
      int o = rnd * 4096 + tid * 16;
      int row = o >> 6, cb = o & 63;
      const u16* gA = A + (size_t)(tm * 128 + row) * 256 + kt * 32 + (cb >> 1);
      const u16* gB = Bw + (size_t)(tn * 128 + row) * 256 + kt * 32 + (cb >> 1);
      GLD16(gA, (char*)sA + o);
      GLD16(gB, (char*)sB + o);
    }
    __syncthreads();
    bf16x8_t af[4], bfr[4];
#pragma unroll
    for (int i = 0; i < 4; ++i)
      af[i] = *(const bf16x8_t*)&sA[(wr * 64 + i * 16 + (lane & 15)) * 32 + (lane >> 4) * 8];
#pragma unroll
    for (int j = 0; j < 4; ++j)
      bfr[j] = *(const bf16x8_t*)&sB[(wc * 64 + j * 16 + (lane & 15)) * 32 + (lane >> 4) * 8];
#pragma unroll
    for (int i = 0; i < 4; ++i)
#pragma unroll
      for (int j = 0; j < 4; ++j)
        acc[i][j] = __builtin_amdgcn_mfma_f32_16x16x32_bf16(af[i], bfr[j], acc[i][j], 0, 0, 0);
  }
  const int r0 = tm * 128 + wr * 64, c0 = tn * 128 + wc * 64;
#pragma unroll
  for (int i = 0; i < 4; ++i)
#pragma unroll
    for (int j = 0; j < 4; ++j)
#pragma unroll
      for (int r = 0; r < 4; ++r) {
        int row = r0 + i * 16 + (lane >> 4) * 4 + r;
        int col = c0 + j * 16 + (lane & 15);
        int b = row / 294, n = row % 294;
        int hx = b >> 4, wy = b & 15;
        int l = n / 49, rem = n % 49, w1 = rem / 7, w2 = rem % 7;
        size_t off = (((((size_t)l * 16 + hx) * 16 + wy) * 7 + w1) * 7 + w2) * 256 + col;
        Cf[off] = acc[i][j][r];
      }
}

// ---------------- fused attention: one block per (window, head) ----------------
// Streaming swapped-operand 32x32x16: per 32-key tile, S^T = mfma(K,Q)+bias ->
// exp2 (no max needed: S bounded, mask=-1e30) -> pack -> permlane -> PV-MFMA.
// Only O (fx16) persists across tiles -> no spills. LDS: swizzled V^T (21 KB).
__device__ __forceinline__ int vt_byte(int d, int tok) {
  return d * 656 + ((d >> 3) & 3) * 32 + tok * 2;
}

__global__ __launch_bounds__(256, 4) void attn(const u16* __restrict__ qkv,
                                               const u16* __restrict__ bias_pre,
                                               u16* __restrict__ aout) {
  __shared__ __align__(16) u16 VT[10560];      // 21120 B
  const int blk = blockIdx.x;
  const int b = blk >> 3, h = blk & 7;
  const int tid = threadIdx.x, lane = tid & 63, wave = tid >> 6;
  const int l31 = lane & 31, g5 = lane >> 5;
  const size_t base = (size_t)b * 294 * 768;

  // build swizzled V^T (zero-fill padded tokens 294..319)
  for (int i = tid; i < 1280; i += 256) {
    int tok = i >> 2, c8 = (i & 3) * 8;
    u16x8_t v;
    if (tok < 294) {
      v = *(const u16x8_t*)(qkv + base + (size_t)tok * 768 + 512 + h * 32 + c8);
    } else {
#pragma unroll
      for (int j = 0; j < 8; ++j) v[j] = 0;
    }
#pragma unroll
    for (int j = 0; j < 8; ++j)
      *(u16*)((char*)VT + vt_byte(c8 + j, tok)) = v[j];
  }
  __syncthreads();

#pragma unroll 1
  for (int s = wave; s < 10; s += 4) {
    // Q B-fragment (row = l31 = query, k = d), two d-halves
    int qr = s * 32 + l31; if (qr > 293) qr = 293;
    const u16* qb = qkv + base + (size_t)qr * 768 + h * 32 + g5 * 8;
    bf16x8_t qf0 = *(const bf16x8_t*)(qb);
    bf16x8_t qf1 = *(const bf16x8_t*)(qb + 16);

    fx16 O;
#pragma unroll
    for (int r = 0; r < 16; ++r) O[r] = 0.f;
    float sv = 0.f;
    const u16* bp = bias_pre + ((size_t)((h * 10 + s) * 10) * 64 + lane) * 16;
    int kr = l31;                              // t*32 + l31, clamped below

#pragma unroll 1
    for (int t = 0; t < 10; ++t) {
      // bias fragment -> f32 C-input
      u16x8_t b0 = *(const u16x8_t*)(bp + t * 1024);
      u16x8_t b1 = *(const u16x8_t*)(bp + t * 1024 + 8);
      fx16 a;
#pragma unroll
      for (int j = 0; j < 8; ++j) { a[j] = bu2f(b0[j]); a[8 + j] = bu2f(b1[j]); }
      // S^T tile = K Q^T + bias
      int krc = kr > 293 ? 293 : kr;
      const u16* kb = qkv + base + (size_t)krc * 768 + 256 + h * 32 + g5 * 8;
      bf16x8_t kf0 = *(const bf16x8_t*)(kb);
      bf16x8_t kf1 = *(const bf16x8_t*)(kb + 16);
      a = __builtin_amdgcn_mfma_f32_32x32x16_bf16(kf0, qf0, a, 0, 0, 0);
      a = __builtin_amdgcn_mfma_f32_32x32x16_bf16(kf1, qf1, a, 0, 0, 0);
      kr += 32;
      // P = exp2(S'), accumulate denom, pack to bf16 pairs
      u32 pk[8];
#pragma unroll
      for (int j = 0; j < 8; ++j) {
        float e0 = __builtin_exp2f(a[2 * j]);
        float e1 = __builtin_exp2f(a[2 * j + 1]);
        sv += e0 + e1;
        pk[j] = (u32)f2bu(e0) | ((u32)f2bu(e1) << 16);
      }
      // PV: A-frag via permlane32_swap redistribution, B-frag from VT
#pragma unroll
      for (int kh = 0; kh < 2; ++kh) {
        u32 w0 = pk[kh * 4 + 0], w1 = pk[kh * 4 + 1];
        u32 w2 = pk[kh * 4 + 2], w3 = pk[kh * 4 + 3];
        plswap(w0, w2);                        // g5=0: k0-7 ; g5=1: k8-15 (of half)
        plswap(w1, w3);
        u32x4_t w; w[0] = w0; w[1] = w1; w[2] = w2; w[3] = w3;
        bf16x8_t pf = __builtin_bit_cast(bf16x8_t, w);
        bf16x8_t vf = *(const bf16x8_t*)((char*)VT + vt_byte(l31, t * 32 + kh * 16 + g5 * 8));
        O = __builtin_amdgcn_mfma_f32_32x32x16_bf16(pf, vf, O, 0, 0, 0);
      }
    }

    sv += __shfl_xor(sv, 32);
    float inv = 1.0f / sv;

    // normalize + store: C-layout row=(r&3)+8*(r>>2)+4*g5 = query, col=l31 = dim
#pragma unroll
    for (int r = 0; r < 16; ++r) {
      int qrow = (r & 3) + 8 * (r >> 2) + 4 * g5;
      int qo = s * 32 + qrow;
      if (qo < 294) {
        float iv = __shfl(inv, qrow);
        aout[((size_t)b * 294 + qo) * 256 + h * 32 + l31] = f2bu(O[r] * iv);
      }
    }
  }
}

extern "C" void kernel_launch(void* const* d_in, const int* in_sizes, int n_in,
                              void* d_out, int out_size, void* d_ws, size_t ws_size,
                              hipStream_t stream) {
  (void)in_sizes; (void)n_in; (void)out_size; (void)ws_size;
  const float* x    = (const float*)d_in[0];
  const float* wqkv = (const float*)d_in[1];
  const float* wout = (const float*)d_in[2];
  const float* btab = (const float*)d_in[3];
  float* out = (float*)d_out;
  char* ws = (char*)d_ws;
  u16* aout  = (u16*)(ws);                     // 75264*256*2   = 38,535,168
  u16* bqkv  = (u16*)(ws + 38535168);          // 768*256*2     =    393,216
  u16* bwout = (u16*)(ws + 38928384);          // 256*256*2     =    131,072
  u16* biasp = (u16*)(ws + 39059456);          // 51200*16*2    =  1,638,400
  u16* qkv   = (u16*)(ws + 40697856);          // 75264*768*2   = 115,605,504 (tot ~149MB)

  prep_w<<<1024, 256, 0, stream>>>(wqkv, wout, bqkv, bwout);
  prep_bias<<<200, 256, 0, stream>>>(btab, biasp);
  gemm_qkv<<<dim3(588, 6), 256, 0, stream>>>(x, bqkv, qkv);
  attn<<<2048, 256, 0, stream>>>(qkv, biasp, aout);
  gemm_proj<<<dim3(588, 2), 256, 0, stream>>>(aout, bwout, out);
}